// Round 4
// baseline (69.110 us; speedup 1.0000x reference)
//
#include <hip/hip_runtime.h>
#include <hip/hip_bf16.h>

#define N_N 128
#define N_C 7
#define N_H 96
#define N_W 192
#define HW (N_H * N_W)            // 18432
#define CHW (N_C * HW)            // 129024
#define NHW (N_N * HW)            // 2359296
#define NPTS 100
#define NK (N_N * N_C)            // 896
#define NK2 (NK / 2)              // 448 float2 per row
#define BG_BLOCKS 1024
#define NPAIR_HALF (NPTS * (NPTS - 1) / 2)   // 4950
#define PAIR_GRID ((NPAIR_HALF + 3) / 4)     // 1238 blocks, 4 waves each
#define SIGMA_F 2.0f

// ---------------- kernel A --------------------------------------------------
// blocks 0..1023   : BCE-with-logits partial sums over channel 0
// blocks 1024..1123: gather row i (transposed) + term1[i]
// block  1124      : zero the K2 accumulators
__global__ __launch_bounds__(256) void fusedA_kernel(
        const float* __restrict__ in, const float* __restrict__ tg,
        const int* __restrict__ px, const int* __restrict__ py,
        double* __restrict__ bgpart,        // [1024]
        float* __restrict__ Pt,             // [100][896]
        float* __restrict__ Gt,             // [100][896]
        float* __restrict__ term1,          // [100]
        double* __restrict__ klacc,         // [1]
        int* __restrict__ cntacc,           // [1]
        int* __restrict__ done) {           // [1]
    __shared__ float sdata[256];
    const int b = blockIdx.x;
    const int t = threadIdx.x;

    if (b == BG_BLOCKS + NPTS) {
        if (t == 0) { *klacc = 0.0; *cntacc = 0; *done = 0; }
        return;
    }

    if (b < BG_BLOCKS) {
        const int NV = NHW / 4;               // 589824
        const int HV = HW / 4;                // 4608
        const int CV = CHW / 4;               // 32256
        const float4* in4 = (const float4*)in;
        const float4* tg4 = (const float4*)tg;
        float s = 0.0f;
        for (int e = b * 256 + t; e < NV; e += BG_BLOCKS * 256) {
            int n = e / HV;
            int r = e - n * HV;
            float4 x4 = in4[n * CV + r];
            float4 t4 = tg4[n * CV + r];
            const float* xp = &x4.x;
            const float* tp = &t4.x;
#pragma unroll
            for (int q = 0; q < 4; ++q) {
                float x = xp[q], tt = tp[q];
                s += fmaxf(x, 0.0f) - x * tt + log1pf(expf(-fabsf(x)));
            }
        }
        sdata[t] = s;
        __syncthreads();
        for (int off = 128; off > 0; off >>= 1) {
            if (t < off) sdata[t] += sdata[t + off];
            __syncthreads();
        }
        if (t == 0) bgpart[b] = (double)sdata[0];
    } else {
        const int i = b - BG_BLOCKS;          // 0..99
        const int base = py[i] * N_W + px[i];
        float s = 0.0f;
        for (int k = t; k < NK; k += 256) {
            int n = k / N_C;
            int c = k - n * N_C;
            int off = n * CHW + c * HW + base;
            float p = in[off];
            float g = tg[off];
            Pt[i * NK + k] = p;
            Gt[i * NK + k] = g;
            s += (p > 0.0f) ? p * logf(p) : 0.0f;
        }
        sdata[t] = s;
        __syncthreads();
        for (int off = 128; off > 0; off >>= 1) {
            if (t < off) sdata[t] += sdata[t + off];
            __syncthreads();
        }
        if (t == 0) term1[i] = sdata[0];
    }
}

// S(i) = number of (a<b) pairs with a < i
__device__ __forceinline__ int rowstart(int i) {
    return i * (2 * NPTS - i - 1) / 2;
}

// ---------------- kernel B: one wave per pair (i<j) + finalization ----------
__global__ __launch_bounds__(256) void pairsfin_kernel(
        const float* __restrict__ Pt, const float* __restrict__ Gt,
        const float* __restrict__ term1,
        const int* __restrict__ px, const int* __restrict__ py,
        const double* __restrict__ bgpart,   // [1024]
        double* __restrict__ klacc,
        int* __restrict__ cntacc,
        int* __restrict__ done,
        float* __restrict__ out) {
    __shared__ double skl[4];
    __shared__ int scnt[4];
    __shared__ int slast;
    __shared__ double sred[256];

    const int t = threadIdx.x;
    const int w = t >> 6;
    const int lane = t & 63;
    const int p = blockIdx.x * 4 + w;     // pair index, 0..4951
    const float2* Pt2 = (const float2*)Pt;
    const float2* Gt2 = (const float2*)Gt;

    double kl = 0.0;
    int cnt = 0;

    if (p < NPAIR_HALF) {
        // decode p -> (i, j) with i < j
        float disc = (float)((2 * NPTS - 1) * (2 * NPTS - 1) - 8 * p);
        int i = (int)(((float)(2 * NPTS - 1) - sqrtf(disc)) * 0.5f);
        if (i < 0) i = 0;
        if (i > NPTS - 2) i = NPTS - 2;
        while (i < NPTS - 2 && rowstart(i + 1) <= p) ++i;
        while (i > 0 && rowstart(i) > p) --i;
        int j = p - rowstart(i) + i + 1;

        // issue all 28 independent coalesced loads, then compute
        float2 piv[7], pjv[7], giv[7], gjv[7];
#pragma unroll
        for (int it = 0; it < 7; ++it) {
            int q = lane + it * 64;
            piv[it] = Pt2[i * NK2 + q];
            pjv[it] = Pt2[j * NK2 + q];
            giv[it] = Gt2[i * NK2 + q];
            gjv[it] = Gt2[j * NK2 + q];
        }
        float cross = 0.0f;
        int eqf = 1;
#pragma unroll
        for (int it = 0; it < 7; ++it) {
            cross = fmaf(piv[it].x, pjv[it].x, cross);
            cross = fmaf(piv[it].y, pjv[it].y, cross);
            eqf &= (giv[it].x == gjv[it].x) & (giv[it].y == gjv[it].y);
        }
#pragma unroll
        for (int m = 32; m >= 1; m >>= 1) cross += __shfl_xor(cross, m);
        int alleq = __all(eqf);
        if (lane == 0) {
            float Dij = (term1[j] - cross) * (1.0f / (float)N_N);
            float Dji = (term1[i] - cross) * (1.0f / (float)N_N);
            float L = alleq ? (Dij + Dji)
                            : (float)(N_N * N_C) *
                              (fmaxf(SIGMA_F - Dij, 0.0f) + fmaxf(SIGMA_F - Dji, 0.0f));
            bool mask = (px[i] != px[j]) && (py[i] != py[j]);
            if (mask) { kl += (double)L; cnt += 1; }
        }
    }

    if (lane == 0) { skl[w] = kl; scnt[w] = cnt; }
    __syncthreads();

    if (t == 0) {
        double klblock = skl[0] + skl[1] + skl[2] + skl[3];
        int cntblock = scnt[0] + scnt[1] + scnt[2] + scnt[3];
        if (klblock != 0.0) atomicAdd(klacc, klblock);
        if (cntblock != 0) atomicAdd(cntacc, cntblock);
        __threadfence();
        int old = atomicAdd(done, 1);
        slast = (old == PAIR_GRID - 1) ? 1 : 0;
    }
    __syncthreads();

    if (slast) {
        // last block: finalize. kl_loss = (2*klhalf)/(2*cnthalf) = klhalf/cnthalf
        double s = 0.0;
        for (int q = t; q < BG_BLOCKS; q += 256) s += bgpart[q];
        sred[t] = s;
        __syncthreads();
        for (int off = 128; off > 0; off >>= 1) {
            if (t < off) sred[t] += sred[t + off];
            __syncthreads();
        }
        if (t == 0) {
            __threadfence();
            double klv = *(volatile double*)klacc;
            int cntv = *(volatile int*)cntacc;
            double bg_loss = sred[0] / (double)NHW;
            out[0] = (float)(bg_loss + klv / (double)cntv);
        }
    }
}

// ---------------- launch ---------------------------------------------------
extern "C" void kernel_launch(void* const* d_in, const int* in_sizes, int n_in,
                              void* d_out, int out_size, void* d_ws, size_t ws_size,
                              hipStream_t stream) {
    const float* inputs  = (const float*)d_in[0];
    const float* targets = (const float*)d_in[1];
    const int*   px      = (const int*)d_in[2];
    const int*   py      = (const int*)d_in[3];
    float* out = (float*)d_out;

    char* ws = (char*)d_ws;
    double* bgpart = (double*)ws;                              // 1024*8 = 8192
    float*  Pt     = (float*)(ws + 8192);                      // 358400
    float*  Gt     = (float*)(ws + 8192 + 358400);             // 358400
    float*  term1  = (float*)(ws + 8192 + 2 * 358400);         // 512 (pad)
    double* klacc  = (double*)(ws + 8192 + 2 * 358400 + 512);  // 8
    int*    cntacc = (int*)(ws + 8192 + 2 * 358400 + 512 + 8);
    int*    done   = (int*)(ws + 8192 + 2 * 358400 + 512 + 16);

    fusedA_kernel<<<BG_BLOCKS + NPTS + 1, 256, 0, stream>>>(
        inputs, targets, px, py, bgpart, Pt, Gt, term1, klacc, cntacc, done);
    pairsfin_kernel<<<PAIR_GRID, 256, 0, stream>>>(
        Pt, Gt, term1, px, py, bgpart, klacc, cntacc, done, out);
}

// Round 5
// 31.722 us; speedup vs baseline: 2.1786x; 2.1786x over previous
//
#include <hip/hip_runtime.h>
#include <hip/hip_bf16.h>

#define N_N 128
#define N_C 7
#define N_H 96
#define N_W 192
#define HW (N_H * N_W)            // 18432
#define CHW (N_C * HW)            // 129024
#define NHW (N_N * HW)            // 2359296
#define NPTS 100
#define NK (N_N * N_C)            // 896
#define NK2 (NK / 2)              // 448 float2 per row
#define NK4 (NK / 4)              // 224 float4 per row
#define BG_BLOCKS 1024
#define TILE 4
#define NTILE (NPTS / TILE)       // 25
#define PAIR_BLOCKS (NTILE * NTILE)  // 625
#define SIGMA_F 2.0f

// ---------------- kernel A --------------------------------------------------
// blocks 0..1023   : BCE-with-logits partial sums over channel 0
// blocks 1024..1123: gather row i (transposed) + term1[i]
__global__ __launch_bounds__(256) void fusedA_kernel(
        const float* __restrict__ in, const float* __restrict__ tg,
        const int* __restrict__ px, const int* __restrict__ py,
        double* __restrict__ bgpart,        // [1024]
        float* __restrict__ Pt,             // [100][896]
        float* __restrict__ Gt,             // [100][896]
        float* __restrict__ term1) {        // [100]
    __shared__ float sdata[256];
    const int b = blockIdx.x;
    const int t = threadIdx.x;

    if (b < BG_BLOCKS) {
        const int NV = NHW / 4;               // 589824
        const int HV = HW / 4;                // 4608
        const int CV = CHW / 4;               // 32256
        const float4* in4 = (const float4*)in;
        const float4* tg4 = (const float4*)tg;
        float s = 0.0f;
        for (int e = b * 256 + t; e < NV; e += BG_BLOCKS * 256) {
            int n = e / HV;
            int r = e - n * HV;
            float4 x4 = in4[n * CV + r];
            float4 t4 = tg4[n * CV + r];
            const float* xp = &x4.x;
            const float* tp = &t4.x;
#pragma unroll
            for (int q = 0; q < 4; ++q) {
                float x = xp[q], tt = tp[q];
                s += fmaxf(x, 0.0f) - x * tt + log1pf(expf(-fabsf(x)));
            }
        }
        sdata[t] = s;
        __syncthreads();
        for (int off = 128; off > 0; off >>= 1) {
            if (t < off) sdata[t] += sdata[t + off];
            __syncthreads();
        }
        if (t == 0) bgpart[b] = (double)sdata[0];
    } else {
        const int i = b - BG_BLOCKS;          // 0..99
        const int base = py[i] * N_W + px[i];
        float s = 0.0f;
        for (int k = t; k < NK; k += 256) {
            int n = k / N_C;
            int c = k - n * N_C;
            int off = n * CHW + c * HW + base;
            float p = in[off];
            float g = tg[off];
            Pt[i * NK + k] = p;
            Gt[i * NK + k] = g;
            s += (p > 0.0f) ? p * logf(p) : 0.0f;
        }
        sdata[t] = s;
        __syncthreads();
        for (int off = 128; off > 0; off >>= 1) {
            if (t < off) sdata[t] += sdata[t + off];
            __syncthreads();
        }
        if (t == 0) term1[i] = sdata[0];
    }
}

// ---------------- kernel B: LDS-tiled pairs ---------------------------------
// 625 blocks; block (ti,tj) owns the 4x4 pair tile. Rows staged in LDS.
__global__ __launch_bounds__(256) void pairs_kernel(
        const float* __restrict__ Pt, const float* __restrict__ Gt,
        const float* __restrict__ term1,
        const int* __restrict__ px, const int* __restrict__ py,
        double* __restrict__ klpart,         // [625]
        int* __restrict__ cntpart) {         // [625]
    __shared__ float sP[8 * NK];             // rows 0-3: i-rows, 4-7: j-rows
    __shared__ float sG[8 * NK];
    __shared__ float sT1[8];
    __shared__ int   sPx[8], sPy[8];
    __shared__ double skl[4];
    __shared__ int scnt[4];

    const int bt = blockIdx.x;
    const int ti = bt / NTILE;
    const int tj = bt - ti * NTILE;
    const int t = threadIdx.x;
    const int w = t >> 6;                    // wave 0..3 == local i index a
    const int lane = t & 63;

    // stage meta for the 8 rows
    if (t < 8) {
        int g = (t < 4) ? (ti * TILE + t) : (tj * TILE + (t - 4));
        sT1[t] = term1[g];
        sPx[t] = px[g];
        sPy[t] = py[g];
    }

    // stage 8 rows of P and G (float4 coalesced): 2*8*224 float4 total
    {
        const float4* Pt4 = (const float4*)Pt;
        const float4* Gt4 = (const float4*)Gt;
        float4* sP4 = (float4*)sP;
        float4* sG4 = (float4*)sG;
        for (int idx = t; idx < 8 * NK4; idx += 256) {
            int r = idx / NK4;
            int q = idx - r * NK4;
            int g = (r < 4) ? (ti * TILE + r) : (tj * TILE + (r - 4));
            sP4[idx] = Pt4[g * NK4 + q];
            sG4[idx] = Gt4[g * NK4 + q];
        }
    }
    __syncthreads();

    const float2* sP2 = (const float2*)sP;
    const float2* sG2 = (const float2*)sG;
    const int I = ti * TILE + w;
    double kl = 0.0;
    int cnt = 0;

#pragma unroll
    for (int b = 0; b < TILE; ++b) {
        const int rj = 4 + b;
        float cross = 0.0f;
        int eqf = 1;
#pragma unroll
        for (int it = 0; it < 7; ++it) {     // 448 float2 / 64 lanes
            int q = lane + it * 64;
            float2 pi = sP2[w * NK2 + q];
            float2 pj = sP2[rj * NK2 + q];
            float2 gi = sG2[w * NK2 + q];
            float2 gj = sG2[rj * NK2 + q];
            cross = fmaf(pi.x, pj.x, cross);
            cross = fmaf(pi.y, pj.y, cross);
            eqf &= (gi.x == gj.x) & (gi.y == gj.y);
        }
#pragma unroll
        for (int m = 32; m >= 1; m >>= 1) cross += __shfl_xor(cross, m);
        int alleq = __all(eqf);
        if (lane == 0) {
            const int J = tj * TILE + b;
            float Dij = (sT1[rj] - cross) * (1.0f / (float)N_N);
            float Dji = (sT1[w] - cross) * (1.0f / (float)N_N);
            float L = alleq ? (Dij + Dji)
                            : (float)(N_N * N_C) *
                              (fmaxf(SIGMA_F - Dij, 0.0f) + fmaxf(SIGMA_F - Dji, 0.0f));
            bool mask = (I != J) && (sPx[w] != sPx[rj]) && (sPy[w] != sPy[rj]);
            if (mask) { kl += (double)L; cnt += 1; }
        }
    }

    if (lane == 0) { skl[w] = kl; scnt[w] = cnt; }
    __syncthreads();
    if (t == 0) {
        klpart[bt] = skl[0] + skl[1] + skl[2] + skl[3];
        cntpart[bt] = scnt[0] + scnt[1] + scnt[2] + scnt[3];
    }
}

// ---------------- kernel C: final scalar ------------------------------------
__global__ __launch_bounds__(256) void final_kernel(
        const double* __restrict__ bgpart,   // [1024]
        const double* __restrict__ klpart,   // [625]
        const int* __restrict__ cntpart,     // [625]
        float* __restrict__ out) {
    __shared__ double sdata[256];
    __shared__ int scnt[256];
    const int t = threadIdx.x;

    double s = 0.0;
    for (int q = t; q < BG_BLOCKS; q += 256) s += bgpart[q];
    double kl = 0.0;
    int cnt = 0;
    for (int q = t; q < PAIR_BLOCKS; q += 256) {
        kl += klpart[q];
        cnt += cntpart[q];
    }
    sdata[t] = s;
    __syncthreads();
    for (int off = 128; off > 0; off >>= 1) {
        if (t < off) sdata[t] += sdata[t + off];
        __syncthreads();
    }
    double bg_sum = sdata[0];
    __syncthreads();
    sdata[t] = kl;
    scnt[t] = cnt;
    __syncthreads();
    for (int off = 128; off > 0; off >>= 1) {
        if (t < off) { sdata[t] += sdata[t + off]; scnt[t] += scnt[t + off]; }
        __syncthreads();
    }
    if (t == 0) {
        double bg_loss = bg_sum / (double)NHW;
        double kl_loss = sdata[0] / (double)scnt[0];
        out[0] = (float)(bg_loss + kl_loss);
    }
}

// ---------------- launch ---------------------------------------------------
extern "C" void kernel_launch(void* const* d_in, const int* in_sizes, int n_in,
                              void* d_out, int out_size, void* d_ws, size_t ws_size,
                              hipStream_t stream) {
    const float* inputs  = (const float*)d_in[0];
    const float* targets = (const float*)d_in[1];
    const int*   px      = (const int*)d_in[2];
    const int*   py      = (const int*)d_in[3];
    float* out = (float*)d_out;

    char* ws = (char*)d_ws;
    double* bgpart  = (double*)ws;                               // 8192
    float*  Pt      = (float*)(ws + 8192);                       // 358400
    float*  Gt      = (float*)(ws + 8192 + 358400);              // 358400
    float*  term1   = (float*)(ws + 8192 + 2 * 358400);          // 512 pad
    double* klpart  = (double*)(ws + 8192 + 2 * 358400 + 512);   // 5000 -> 5120
    int*    cntpart = (int*)(ws + 8192 + 2 * 358400 + 512 + 5120); // 2500

    fusedA_kernel<<<BG_BLOCKS + NPTS, 256, 0, stream>>>(
        inputs, targets, px, py, bgpart, Pt, Gt, term1);
    pairs_kernel<<<PAIR_BLOCKS, 256, 0, stream>>>(
        Pt, Gt, term1, px, py, klpart, cntpart);
    final_kernel<<<1, 256, 0, stream>>>(bgpart, klpart, cntpart, out);
}